// Round 2
// baseline (240.744 us; speedup 1.0000x reference)
//
#include <hip/hip_runtime.h>

#define E_EDGES 1000000
#define NNODES  100000
#define HID     128
#define NG      31250     // 32-edge groups, exact
#define NBLK    512       // 2 blocks/CU x 256 CUs

typedef float f32x4 __attribute__((ext_vector_type(4)));
typedef short s16x8 __attribute__((ext_vector_type(8)));

typedef __attribute__((address_space(3))) unsigned int lds_u32;
typedef const __attribute__((address_space(1))) unsigned int glb_u32;

// async 16B/lane global->LDS: per-lane global addr, wave-uniform LDS base +
// lane*16 deposit. Completion tracked via counted vmcnt (raw s_barrier, no
// compiler drain) -- depth-2 pipeline.
__device__ __forceinline__ void gl_lds16(const void* g, void* l) {
  __builtin_amdgcn_global_load_lds((glb_u32*)g, (lds_u32*)l, 16, 0, 0);
}

#define WAITVM(N)  asm volatile("s_waitcnt vmcnt(" #N ")" ::: "memory")
#define WAITLGKM0  asm volatile("s_waitcnt lgkmcnt(0)" ::: "memory")
#define SFENCE     __builtin_amdgcn_sched_barrier(0)
#define BAR()      do { SFENCE; __builtin_amdgcn_s_barrier(); SFENCE; } while (0)

// float -> bf16, round-to-nearest-even (inputs are finite)
__device__ __forceinline__ unsigned short f2bf(float f) {
  unsigned int u = __float_as_uint(f);
  u += 0x7FFFu + ((u >> 16) & 1u);
  return (unsigned short)(u >> 16);
}

__device__ __forceinline__ int4 pack8(float4 a, float4 b) {
  int4 v;
  v.x = (int)((unsigned)f2bf(a.x) | ((unsigned)f2bf(a.y) << 16));
  v.y = (int)((unsigned)f2bf(a.z) | ((unsigned)f2bf(a.w) << 16));
  v.z = (int)((unsigned)f2bf(b.x) | ((unsigned)f2bf(b.y) << 16));
  v.w = (int)((unsigned)f2bf(b.z) | ((unsigned)f2bf(b.w) << 16));
  return v;
}

__global__ void cast_x_kernel(const float* __restrict__ x,
                              unsigned short* __restrict__ xb) {
  int i = blockIdx.x * blockDim.x + threadIdx.x;
  const float4* p = (const float4*)x;
  float4 a = p[2 * i];
  float4 b = p[2 * i + 1];
  int4 v = pack8(a, b);
  ((int4*)xb)[i] = v;
}

// Correct-but-slow insurance path if workspace is too small for bf16 x.
__global__ void edge_naive(const float* __restrict__ x, const int* __restrict__ ei,
                           const float* __restrict__ attr, const float* __restrict__ W1,
                           const float* __restrict__ b1, const float* __restrict__ W2,
                           const float* __restrict__ b2, const float* __restrict__ W3,
                           const float* __restrict__ b3, float* __restrict__ out) {
  const int e = blockIdx.x * blockDim.x + threadIdx.x;
  if (e >= E_EDGES) return;
  const float* xs = x + (size_t)ei[e] * HID;
  const float* xd = x + (size_t)ei[E_EDGES + e] * HID;
  const float a = attr[e];
  float h1[HID];
  for (int n = 0; n < HID; ++n) {
    float s = b1[n] + a * W1[256 * HID + n];
    for (int k = 0; k < HID; ++k)
      s += xs[k] * W1[k * HID + n] + xd[k] * W1[(128 + k) * HID + n];
    h1[n] = fmaxf(s, 0.f);
  }
  float o = b3[0];
  for (int n2 = 0; n2 < 32; ++n2) {
    float s = b2[n2];
    for (int n = 0; n < HID; ++n) s += h1[n] * W2[n * 32 + n2];
    o += fmaxf(s, 0.f) * W3[n2];
  }
  out[e] = 1.f / (1.f + __expf(-o));
}

// meta staging: one gl_lds16 per group stages BOTH nids and attr into LDS.
// lane l deposits at meta+l*16:
//   lanes 0..7  -> src nids  ei[g*32 .. +32)          at bytes [0,128)
//   lanes 8..15 -> dst nids  ei[E + g*32 ..)          at bytes [128,256)
//   lanes 16..23-> attr      attr[g*32 .. +32)        at bytes [256,384)
//   lanes 24..63-> attr dupes (junk, never read)      at bytes [384,1024)
__device__ __forceinline__ const void* meta_src(const int* ei, const float* attr,
                                                int G, int lane) {
  const char* p;
  if (lane < 8)       p = (const char*)ei + (size_t)G * 128 + lane * 16;
  else if (lane < 16) p = (const char*)ei + (size_t)E_EDGES * 4 + (size_t)G * 128 + (lane - 8) * 16;
  else                p = (const char*)attr + (size_t)G * 128 + (lane & 7) * 16;
  return p;
}

// 256 threads = 4 waves; 32-edge groups; grid-stride by NBLK.
// Counted-vmcnt depth-2 gather pipeline (no __syncthreads drains):
//   slot(it) = it&3 (4 ef/meta buffers).
//   epoch it (computes g = bx + it*NBLK):
//     WAITVM(10)             ; DMA batch(it-3) [ef(g), meta(g+N)] done; only
//                              batches(it-2,it-1) (= 2x5 ops) may remain.
//     LGKM0 ; BARRIER        ; ef/meta readable by all waves; red visible
//     L1(g): ef[P]+meta attr -> MFMA -> h1b  (single h1 buffer)
//     LGKM0 ; BARRIER        ; h1 visible
//     L2(g): h1b -> MFMA -> shfl-reduce -> red[it&1]
//     out(g-NBLK) from red[(it&1)^1]
//     tail (if g+3N < NG): WAITVM(4) -> ds_read nids(g+3N) from meta ->
//       issue batch(it) = [meta(g+4N clamped), ef(g+3N)x4]
// All waits are "old op done, allow <=N newer": compiler-added VMEM ops can
// only over-drain (perf), never break correctness.
__launch_bounds__(256, 2)
__global__ void edge_mlp_kernel(const unsigned short* __restrict__ xb,
                                const int* __restrict__ ei,
                                const float* __restrict__ attr,
                                const float* __restrict__ W1,
                                const float* __restrict__ b1,
                                const float* __restrict__ W2,
                                const float* __restrict__ b2,
                                const float* __restrict__ W3,
                                const float* __restrict__ b3,
                                float* __restrict__ out) {
  __shared__ __align__(16) unsigned char ef[4][16384];   // 64 KB
  __shared__ __align__(16) unsigned char meta[4][1024];  // 4 KB
  __shared__ __align__(16) unsigned char h1b[8704];      // 8.5 KB
  __shared__ float red[2][4][16];                        // 512 B

  const int tid  = threadIdx.x;
  const int w    = tid >> 6;
  const int lane = tid & 63;
  const int q    = lane >> 4;
  const int l15  = lane & 15;

  // ---- L1 weights: wave w owns output cols w*32 .. w*32+31 (2 col-tiles) ----
  s16x8 B1[2][8];
  float b1v[2], w1l[2];
#pragma unroll
  for (int th = 0; th < 2; ++th) {
    const int nc = w * 32 + th * 16 + l15;
#pragma unroll
    for (int s = 0; s < 8; ++s)
#pragma unroll
      for (int j = 0; j < 8; ++j)
        B1[th][s][j] = (short)f2bf(W1[(s * 32 + q * 8 + j) * HID + nc]);
    b1v[th] = b1[nc];
    w1l[th] = W1[256 * HID + nc];   // attr column (k=256)
  }
  // ---- L2 weights: wave w -> tile w>>1, half w&1; k in h1 storage order ----
  const int n2 = (w & 1) * 16 + l15;
  s16x8 B2[4];
#pragma unroll
  for (int s2 = 0; s2 < 4; ++s2)
#pragma unroll
    for (int j = 0; j < 8; ++j) {
      const int e = s2 * 32 + q * 8 + j;                       // storage index
      const int n = (e >> 5) * 32 + (e & 1) * 16 + ((e >> 1) & 15);
      B2[s2][j] = (short)f2bf(W2[n * 32 + n2]);
    }
  const float b2v = b2[n2];
  const float w3v = W3[n2];
  const float b3v = b3[0];

  const int bx = blockIdx.x;

  // ---- prologue: stage meta(g0..g3) + ef(g0..g2) ----
  {
    int nid[4];
    gl_lds16(meta_src(ei, attr, bx, lane), &meta[0][0]);
    WAITVM(0);
#pragma unroll
    for (int i = 0; i < 4; ++i) {
      const int f = w * 4 + i;
      nid[i] = *(const int*)&meta[0][(f >> 3) * 128 + ((f & 7) * 4 + q) * 4];
    }
    gl_lds16(meta_src(ei, attr, bx + NBLK, lane), &meta[1][0]);
    SFENCE;
#pragma unroll
    for (int i = 0; i < 4; ++i) {
      const int f = w * 4 + i, m = (f & 7) * 4 + q;
      gl_lds16(xb + (size_t)nid[i] * HID + ((l15 ^ (m & 7)) << 3), &ef[0][f * 1024]);
    }
    WAITVM(4);   // meta(g1) done; ef(g0) may remain
#pragma unroll
    for (int i = 0; i < 4; ++i) {
      const int f = w * 4 + i;
      nid[i] = *(const int*)&meta[1][(f >> 3) * 128 + ((f & 7) * 4 + q) * 4];
    }
    gl_lds16(meta_src(ei, attr, bx + 2 * NBLK, lane), &meta[2][0]);
    SFENCE;
#pragma unroll
    for (int i = 0; i < 4; ++i) {
      const int f = w * 4 + i, m = (f & 7) * 4 + q;
      gl_lds16(xb + (size_t)nid[i] * HID + ((l15 ^ (m & 7)) << 3), &ef[1][f * 1024]);
    }
    WAITVM(4);   // meta(g2) done (also drains ef(g0)); ef(g1) may remain
#pragma unroll
    for (int i = 0; i < 4; ++i) {
      const int f = w * 4 + i;
      nid[i] = *(const int*)&meta[2][(f >> 3) * 128 + ((f & 7) * 4 + q) * 4];
    }
    gl_lds16(meta_src(ei, attr, bx + 3 * NBLK, lane), &meta[3][0]);
    SFENCE;
#pragma unroll
    for (int i = 0; i < 4; ++i) {
      const int f = w * 4 + i, m = (f & 7) * 4 + q;
      gl_lds16(xb + (size_t)nid[i] * HID + ((l15 ^ (m & 7)) << 3), &ef[2][f * 1024]);
    }
  }

  const int T = (NG - 1 - bx) / NBLK + 1;   // it = 0..T (last epoch = drain)

  for (int it = 0; it <= T; ++it) {
    const int g   = bx + it * NBLK;
    const int P   = it & 3;
    const int par = it & 1;
    const int gm1 = g - NBLK;

    if (g + 2 * NBLK < NG) { WAITVM(10); } else { WAITVM(0); }
    WAITLGKM0;
    BAR();

    if (g < NG) {
      const f32x4 at0 = *(const f32x4*)&meta[P][256 + q * 16];
      const f32x4 at1 = *(const f32x4*)&meta[P][256 + 64 + q * 16];
#pragma unroll
      for (int t = 0; t < 2; ++t) {
        f32x4 a0 = {0.f, 0.f, 0.f, 0.f}, a1 = {0.f, 0.f, 0.f, 0.f};
#pragma unroll
        for (int s = 0; s < 8; ++s) {
          const int ch = s * 4 + q;
          const s16x8 A = *(const s16x8*)&ef[P][(ch >> 4) * 8192 + t * 4096
              + l15 * 256 + (((ch & 15) ^ (l15 & 7)) << 4)];
          a0 = __builtin_amdgcn_mfma_f32_16x16x32_bf16(A, B1[0][s], a0, 0, 0, 0);
          a1 = __builtin_amdgcn_mfma_f32_16x16x32_bf16(A, B1[1][s], a1, 0, 0, 0);
        }
        const f32x4 at = t ? at1 : at0;
#pragma unroll
        for (int r = 0; r < 4; ++r) {
          const float v0 = fmaxf(a0[r] + b1v[0] + at[r] * w1l[0], 0.f);
          const float v1 = fmaxf(a1[r] + b1v[1] + at[r] * w1l[1], 0.f);
          const unsigned int pk =
              (unsigned)f2bf(v0) | ((unsigned)f2bf(v1) << 16);
          *(unsigned int*)&h1b[t * 4352 + (q * 4 + r) * 272
                               + (w * 16 + l15) * 4] = pk;
        }
      }
    }

    WAITLGKM0;
    BAR();

    if (g < NG) {
      const int t = w >> 1;
      f32x4 c0 = {0.f, 0.f, 0.f, 0.f};
#pragma unroll
      for (int s2 = 0; s2 < 4; ++s2) {
        const s16x8 A2 = *(const s16x8*)&h1b[t * 4352 + l15 * 272
                                             + s2 * 64 + q * 16];
        c0 = __builtin_amdgcn_mfma_f32_16x16x32_bf16(A2, B2[s2], c0, 0, 0, 0);
      }
      float p0 = fmaxf(c0[0] + b2v, 0.f) * w3v;
      float p1 = fmaxf(c0[1] + b2v, 0.f) * w3v;
      float p2 = fmaxf(c0[2] + b2v, 0.f) * w3v;
      float p3 = fmaxf(c0[3] + b2v, 0.f) * w3v;
#pragma unroll
      for (int off = 8; off >= 1; off >>= 1) {
        p0 += __shfl_xor(p0, off, 16);
        p1 += __shfl_xor(p1, off, 16);
        p2 += __shfl_xor(p2, off, 16);
        p3 += __shfl_xor(p3, off, 16);
      }
      if (l15 == 0) {
        red[par][w][q * 4 + 0] = p0;
        red[par][w][q * 4 + 1] = p1;
        red[par][w][q * 4 + 2] = p2;
        red[par][w][q * 4 + 3] = p3;
      }
    }

    if (gm1 >= 0 && tid < 32) {
      const int tt = tid >> 4, mm = tid & 15;
      const float sv = red[par ^ 1][tt * 2][mm]
                     + red[par ^ 1][tt * 2 + 1][mm] + b3v;
      out[gm1 * 32 + tid] = 1.f / (1.f + __expf(-sv));
    }

    const int g3 = g + 3 * NBLK;
    if (g3 < NG) {
      WAITVM(4);   // meta(g3) (op-1 of batch it-1) done; ef(g+2N) may remain
      const int P3 = (P + 3) & 3;
      int nid[4];
#pragma unroll
      for (int i = 0; i < 4; ++i) {
        const int f = w * 4 + i;
        nid[i] = *(const int*)&meta[P3][(f >> 3) * 128 + ((f & 7) * 4 + q) * 4];
      }
      int g4 = g + 4 * NBLK;
      if (g4 > NG - 1) g4 = NG - 1;   // clamp: keeps batch op-count = 5 exact
      gl_lds16(meta_src(ei, attr, g4, lane), &meta[P][0]);
      SFENCE;
#pragma unroll
      for (int i = 0; i < 4; ++i) {
        const int f = w * 4 + i, m = (f & 7) * 4 + q;
        gl_lds16(xb + (size_t)nid[i] * HID + ((l15 ^ (m & 7)) << 3),
                 &ef[P3][f * 1024]);
      }
    }
  }
}

extern "C" void kernel_launch(void* const* d_in, const int* in_sizes, int n_in,
                              void* d_out, int out_size, void* d_ws, size_t ws_size,
                              hipStream_t stream) {
  const float* x    = (const float*)d_in[0];
  const int*   ei   = (const int*)d_in[1];
  const float* attr = (const float*)d_in[2];
  const float* W1   = (const float*)d_in[3];
  const float* b1   = (const float*)d_in[4];
  const float* W2   = (const float*)d_in[5];
  const float* b2   = (const float*)d_in[6];
  const float* W3   = (const float*)d_in[7];
  const float* b3   = (const float*)d_in[8];
  float* out = (float*)d_out;

  const size_t need = (size_t)NNODES * HID * sizeof(unsigned short);  // 25.6 MB
  if (ws_size >= need) {
    unsigned short* xb = (unsigned short*)d_ws;
    cast_x_kernel<<<6250, 256, 0, stream>>>(x, xb);
    edge_mlp_kernel<<<NBLK, 256, 0, stream>>>(xb, ei, attr, W1, b1, W2, b2, W3, b3, out);
  } else {
    edge_naive<<<(E_EDGES + 255) / 256, 256, 0, stream>>>(x, ei, attr, W1, b1, W2, b2, W3, b3, out);
  }
}

// Round 3
// 205.850 us; speedup vs baseline: 1.1695x; 1.1695x over previous
//
#include <hip/hip_runtime.h>

#define E_EDGES 1000000
#define NNODES  100000
#define HID     128
#define NG      31250     // 32-edge groups (old path)
#define NBLK    768       // old-path grid
#define NT      62500     // 16-edge tiles (new path)
#define EBLK    768       // new-path blocks: 3/CU x 256 CUs

typedef float f32x4 __attribute__((ext_vector_type(4)));
typedef short s16x8 __attribute__((ext_vector_type(8)));

typedef __attribute__((address_space(3))) unsigned int lds_u32;
typedef const __attribute__((address_space(1))) unsigned int glb_u32;

__device__ __forceinline__ void gl_lds16(const void* g, void* l) {
  __builtin_amdgcn_global_load_lds((glb_u32*)g, (lds_u32*)l, 16, 0, 0);
}

// float -> bf16, round-to-nearest-even (inputs are finite)
__device__ __forceinline__ unsigned short f2bf(float f) {
  unsigned int u = __float_as_uint(f);
  u += 0x7FFFu + ((u >> 16) & 1u);
  return (unsigned short)(u >> 16);
}

__device__ __forceinline__ unsigned int cvtpk_bf16(float lo, float hi) {
  unsigned int r;
  asm("v_cvt_pk_bf16_f32 %0, %1, %2" : "=v"(r) : "v"(lo), "v"(hi));
  return r;
}

__device__ __forceinline__ float bflo(unsigned int u) {
  return __uint_as_float(u << 16);
}
__device__ __forceinline__ float bfhi(unsigned int u) {
  return __uint_as_float(u & 0xffff0000u);
}

__device__ __forceinline__ int4 pack8(float4 a, float4 b) {
  int4 v;
  v.x = (int)((unsigned)f2bf(a.x) | ((unsigned)f2bf(a.y) << 16));
  v.y = (int)((unsigned)f2bf(a.z) | ((unsigned)f2bf(a.w) << 16));
  v.z = (int)((unsigned)f2bf(b.x) | ((unsigned)f2bf(b.y) << 16));
  v.w = (int)((unsigned)f2bf(b.z) | ((unsigned)f2bf(b.w) << 16));
  return v;
}

__global__ void cast_x_kernel(const float* __restrict__ x,
                              unsigned short* __restrict__ xb) {
  int i = blockIdx.x * blockDim.x + threadIdx.x;
  const float4* p = (const float4*)x;
  float4 a = p[2 * i];
  float4 b = p[2 * i + 1];
  int4 v = pack8(a, b);
  ((int4*)xb)[i] = v;
}

// Correct-but-slow insurance path if workspace is tiny.
__global__ void edge_naive(const float* __restrict__ x, const int* __restrict__ ei,
                           const float* __restrict__ attr, const float* __restrict__ W1,
                           const float* __restrict__ b1, const float* __restrict__ W2,
                           const float* __restrict__ b2, const float* __restrict__ W3,
                           const float* __restrict__ b3, float* __restrict__ out) {
  const int e = blockIdx.x * blockDim.x + threadIdx.x;
  if (e >= E_EDGES) return;
  const float* xs = x + (size_t)ei[e] * HID;
  const float* xd = x + (size_t)ei[E_EDGES + e] * HID;
  const float a = attr[e];
  float h1[HID];
  for (int n = 0; n < HID; ++n) {
    float s = b1[n] + a * W1[256 * HID + n];
    for (int k = 0; k < HID; ++k)
      s += xs[k] * W1[k * HID + n] + xd[k] * W1[(128 + k) * HID + n];
    h1[n] = fmaxf(s, 0.f);
  }
  float o = b3[0];
  for (int n2 = 0; n2 < 32; ++n2) {
    float s = b2[n2];
    for (int n = 0; n < HID; ++n) s += h1[n] * W2[n * 32 + n2];
    o += fmaxf(s, 0.f) * W3[n2];
  }
  out[e] = 1.f / (1.f + __expf(-o));
}

// ---------------------------------------------------------------------------
// OLD verified path (232 us) -- fallback when ws in [25.6, 51.2) MB.
// ---------------------------------------------------------------------------
__launch_bounds__(256, 3)
__global__ void edge_mlp_kernel(const unsigned short* __restrict__ xb,
                                const int* __restrict__ ei,
                                const float* __restrict__ attr,
                                const float* __restrict__ W1,
                                const float* __restrict__ b1,
                                const float* __restrict__ W2,
                                const float* __restrict__ b2,
                                const float* __restrict__ W3,
                                const float* __restrict__ b3,
                                float* __restrict__ out) {
  __shared__ __align__(16) unsigned char ef[2][16384];
  __shared__ __align__(16) unsigned char h1b[2][8704];
  __shared__ float red[2][4][16];

  const int tid  = threadIdx.x;
  const int w    = tid >> 6;
  const int lane = tid & 63;
  const int q    = lane >> 4;
  const int l15  = lane & 15;

  s16x8 B1[2][8];
  float b1v[2], w1l[2];
#pragma unroll
  for (int th = 0; th < 2; ++th) {
    const int nc = w * 32 + th * 16 + l15;
#pragma unroll
    for (int s = 0; s < 8; ++s)
#pragma unroll
      for (int j = 0; j < 8; ++j)
        B1[th][s][j] = (short)f2bf(W1[(s * 32 + q * 8 + j) * HID + nc]);
    b1v[th] = b1[nc];
    w1l[th] = W1[256 * HID + nc];
  }
  const int n2 = (w & 1) * 16 + l15;
  s16x8 B2[4];
#pragma unroll
  for (int s2 = 0; s2 < 4; ++s2)
#pragma unroll
    for (int j = 0; j < 8; ++j) {
      const int e = s2 * 32 + q * 8 + j;
      const int n = (e >> 5) * 32 + (e & 1) * 16 + ((e >> 1) & 15);
      B2[s2][j] = (short)f2bf(W2[n * 32 + n2]);
    }
  const float b2v = b2[n2];
  const float w3v = W3[n2];
  const float b3v = b3[0];

  const int bx = blockIdx.x;
  int nidA[4] = {0, 0, 0, 0}, nidB[4] = {0, 0, 0, 0};
  const int itmax = (NG - 1 - bx) / NBLK + 2;

  {
#pragma unroll
    for (int i = 0; i < 4; ++i) {
      const int f = w * 4 + i;
      nidA[i] = ei[(f >> 3) * E_EDGES + bx * 32 + (f & 7) * 4 + q];
    }
#pragma unroll
    for (int i = 0; i < 4; ++i) {
      const int f = w * 4 + i, m = (f & 7) * 4 + q;
      gl_lds16(xb + (size_t)nidA[i] * HID + ((l15 ^ (m & 7)) << 3),
               &ef[0][f * 1024]);
    }
    const int g1 = bx + NBLK;
    if (g1 < NG) {
#pragma unroll
      for (int i = 0; i < 4; ++i) {
        const int f = w * 4 + i;
        nidB[i] = ei[(f >> 3) * E_EDGES + g1 * 32 + (f & 7) * 4 + q];
      }
    }
  }
  __syncthreads();

#define ITER(IT, P, NIDU, NIDL)                                               \
  {                                                                           \
    const int g   = bx + (IT) * NBLK;                                         \
    const int g1  = g + NBLK;                                                 \
    const int g2  = g + 2 * NBLK;                                             \
    const int gm1 = g - NBLK;                                                 \
    const int gm2 = g - 2 * NBLK;                                             \
    if (g1 < NG) {                                                            \
      _Pragma("unroll") for (int i = 0; i < 4; ++i) {                         \
        const int f = w * 4 + i, m = (f & 7) * 4 + q;                         \
        gl_lds16(xb + (size_t)NIDU[i] * HID + ((l15 ^ (m & 7)) << 3),         \
                 &ef[(P) ^ 1][f * 1024]);                                     \
      }                                                                       \
    }                                                                         \
    if (g2 < NG) {                                                            \
      _Pragma("unroll") for (int i = 0; i < 4; ++i) {                         \
        const int f = w * 4 + i;                                              \
        NIDL[i] = ei[(f >> 3) * E_EDGES + g2 * 32 + (f & 7) * 4 + q];         \
      }                                                                       \
    }                                                                         \
    if (g < NG) {                                                             \
      const f32x4 at0 = *(const f32x4*)(attr + g * 32 + q * 4);               \
      const f32x4 at1 = *(const f32x4*)(attr + g * 32 + 16 + q * 4);          \
      _Pragma("unroll") for (int t = 0; t < 2; ++t) {                         \
        f32x4 a0 = {0.f, 0.f, 0.f, 0.f}, a1 = {0.f, 0.f, 0.f, 0.f};          \
        _Pragma("unroll") for (int s = 0; s < 8; ++s) {                       \
          const int ch = s * 4 + q;                                           \
          const s16x8 A = *(const s16x8*)&ef[P][(ch >> 4) * 8192 + t * 4096   \
              + l15 * 256 + (((ch & 15) ^ (l15 & 7)) << 4)];                  \
          a0 = __builtin_amdgcn_mfma_f32_16x16x32_bf16(A, B1[0][s], a0, 0, 0, 0); \
          a1 = __builtin_amdgcn_mfma_f32_16x16x32_bf16(A, B1[1][s], a1, 0, 0, 0); \
        }                                                                     \
        const f32x4 at = t ? at1 : at0;                                       \
        _Pragma("unroll") for (int r = 0; r < 4; ++r) {                       \
          const float v0 = fmaxf(a0[r] + b1v[0] + at[r] * w1l[0], 0.f);       \
          const float v1 = fmaxf(a1[r] + b1v[1] + at[r] * w1l[1], 0.f);       \
          const unsigned int pk =                                             \
              (unsigned)f2bf(v0) | ((unsigned)f2bf(v1) << 16);                \
          *(unsigned int*)&h1b[P][t * 4352 + (q * 4 + r) * 272                \
                                  + (w * 16 + l15) * 4] = pk;                 \
        }                                                                     \
      }                                                                       \
    }                                                                         \
    if (gm1 >= 0 && gm1 < NG) {                                               \
      const int t = w >> 1;                                                   \
      f32x4 c0 = {0.f, 0.f, 0.f, 0.f};                                        \
      _Pragma("unroll") for (int s2 = 0; s2 < 4; ++s2) {                      \
        const s16x8 A2 = *(const s16x8*)&h1b[(P) ^ 1][t * 4352 + l15 * 272    \
                                                      + s2 * 64 + q * 16];    \
        c0 = __builtin_amdgcn_mfma_f32_16x16x32_bf16(A2, B2[s2], c0, 0, 0, 0); \
      }                                                                       \
      float p0 = fmaxf(c0[0] + b2v, 0.f) * w3v;                               \
      float p1 = fmaxf(c0[1] + b2v, 0.f) * w3v;                               \
      float p2 = fmaxf(c0[2] + b2v, 0.f) * w3v;                               \
      float p3 = fmaxf(c0[3] + b2v, 0.f) * w3v;                               \
      _Pragma("unroll") for (int off = 8; off >= 1; off >>= 1) {              \
        p0 += __shfl_xor(p0, off, 16);                                        \
        p1 += __shfl_xor(p1, off, 16);                                        \
        p2 += __shfl_xor(p2, off, 16);                                        \
        p3 += __shfl_xor(p3, off, 16);                                        \
      }                                                                       \
      if (l15 == 0) {                                                         \
        red[P][w][q * 4 + 0] = p0;                                            \
        red[P][w][q * 4 + 1] = p1;                                            \
        red[P][w][q * 4 + 2] = p2;                                            \
        red[P][w][q * 4 + 3] = p3;                                            \
      }                                                                       \
    }                                                                         \
    if (gm2 >= 0 && tid < 32) {                                               \
      const int tt = tid >> 4, mm = tid & 15;                                 \
      const float sv = red[(P) ^ 1][tt * 2][mm]                               \
                     + red[(P) ^ 1][tt * 2 + 1][mm] + b3v;                    \
      out[gm2 * 32 + tid] = 1.f / (1.f + __expf(-sv));                        \
    }                                                                         \
    __syncthreads();                                                          \
  }

  for (int itb = 0;; itb += 2) {
    ITER(itb, 0, nidB, nidA)
    if (itb >= itmax) break;
    ITER(itb + 1, 1, nidA, nidB)
    if (itb + 1 >= itmax) break;
  }
#undef ITER
}

// ---------------------------------------------------------------------------
// NEW path: per-node precompute Pa = x@W1[0:128] + b1/2, Pb = x@W1[128:256] + b1/2
// (bf16 out). Edge kernel becomes gather + elementwise + tiny L2/L3 MLP.
// ---------------------------------------------------------------------------
__global__ void node_precompute(const float* __restrict__ x,
                                const float* __restrict__ W1,
                                const float* __restrict__ b1,
                                unsigned short* __restrict__ Pa,
                                unsigned short* __restrict__ Pb) {
  __shared__ __align__(16) unsigned char xs[32 * 272];   // 32 rows x 256B + 16B pad
  const int tid = threadIdx.x;
  const int w = tid >> 6, lane = tid & 63, q = lane >> 4, l15 = lane & 15;
  const int n0 = blockIdx.x * 32;

  // stage 32 node rows f32 -> bf16 into LDS (row stride 272B)
  {
    const int r = tid >> 3, cc = tid & 7;
    const float* src = x + (size_t)(n0 + r) * HID + cc * 16;
    float4 f0 = ((const float4*)src)[0];
    float4 f1 = ((const float4*)src)[1];
    float4 f2 = ((const float4*)src)[2];
    float4 f3 = ((const float4*)src)[3];
    *(int4*)&xs[r * 272 + cc * 32]      = pack8(f0, f1);
    *(int4*)&xs[r * 272 + cc * 32 + 16] = pack8(f2, f3);
  }
  __syncthreads();

  // wave w covers global out-cols w*64 .. +63; col c: side=c>>7, n=c&127
  s16x8 Bf[4][4];
  float bh[4];
  int sides[4], ncols[4];
#pragma unroll
  for (int nt = 0; nt < 4; ++nt) {
    const int c = w * 64 + nt * 16 + l15;
    const int side = c >> 7, n = c & 127;
    sides[nt] = side; ncols[nt] = n;
    bh[nt] = 0.5f * b1[n];
#pragma unroll
    for (int s = 0; s < 4; ++s)
#pragma unroll
      for (int j = 0; j < 8; ++j)
        Bf[nt][s][j] = (short)f2bf(W1[(side * 128 + s * 32 + q * 8 + j) * HID + n]);
  }

#pragma unroll
  for (int mt = 0; mt < 2; ++mt) {
    s16x8 A[4];
#pragma unroll
    for (int s = 0; s < 4; ++s)
      A[s] = *(const s16x8*)&xs[(mt * 16 + l15) * 272 + (s * 4 + q) * 16];
#pragma unroll
    for (int nt = 0; nt < 4; ++nt) {
      f32x4 acc = {0.f, 0.f, 0.f, 0.f};
#pragma unroll
      for (int s = 0; s < 4; ++s)
        acc = __builtin_amdgcn_mfma_f32_16x16x32_bf16(A[s], Bf[nt][s], acc, 0, 0, 0);
      unsigned short* dst = sides[nt] ? Pb : Pa;
#pragma unroll
      for (int r = 0; r < 4; ++r) {
        const int node = n0 + mt * 16 + q * 4 + r;
        dst[(size_t)node * HID + ncols[nt]] = f2bf(acc[r] + bh[nt]);
      }
    }
  }
}

// Independent-wave edge kernel: per 16-edge tile, register gather of
// Pa[src]/Pb[dst] 16B slices straight into the L2 MFMA A-fragment layout
// (lane(q,l15): edge row l15, k = s*32+q*8..+8). No LDS, no barriers.
__launch_bounds__(256, 3)
__global__ void edge_mlp2(const unsigned short* __restrict__ Pa,
                          const unsigned short* __restrict__ Pb,
                          const int* __restrict__ ei,
                          const float* __restrict__ attr,
                          const float* __restrict__ W1,
                          const float* __restrict__ W2,
                          const float* __restrict__ b2,
                          const float* __restrict__ W3,
                          const float* __restrict__ b3,
                          float* __restrict__ out) {
  const int tid = threadIdx.x;
  const int w = tid >> 6, lane = tid & 63, q = lane >> 4, l15 = lane & 15;
  const int wid = blockIdx.x * 4 + w;
  const int nw  = EBLK * 4;

  // L2 weight fragments, natural k order: B[k][col], col = l15 / l15+16
  s16x8 B2a[4], B2b[4];
#pragma unroll
  for (int s = 0; s < 4; ++s)
#pragma unroll
    for (int j = 0; j < 8; ++j) {
      const int k = s * 32 + q * 8 + j;
      B2a[s][j] = (short)f2bf(W2[k * 32 + l15]);
      B2b[s][j] = (short)f2bf(W2[k * 32 + 16 + l15]);
    }
  // attr column of W1 (k=256), packed bf16: w1p[s] covers k = s*32+q*8 .. +8
  int4 w1p[4];
#pragma unroll
  for (int s = 0; s < 4; ++s) {
    unsigned int uu[4];
#pragma unroll
    for (int m = 0; m < 4; ++m) {
      const int k = s * 32 + q * 8 + 2 * m;
      uu[m] = (unsigned)f2bf(W1[256 * HID + k]) |
              ((unsigned)f2bf(W1[256 * HID + k + 1]) << 16);
    }
    w1p[s] = make_int4((int)uu[0], (int)uu[1], (int)uu[2], (int)uu[3]);
  }
  const float b2a = b2[l15], b2b = b2[16 + l15];
  const float w3a = W3[l15], w3b = W3[16 + l15];
  const float b3v = b3[0];

  int t = wid;
  if (t >= NT) return;
  int sid = ei[t * 16 + l15];
  int did = ei[E_EDGES + t * 16 + l15];
  float at = attr[t * 16 + l15];

  while (true) {
    // gather current tile's A-operand slices (16B per lane per s per side)
    const unsigned short* pa = Pa + (size_t)sid * HID;
    const unsigned short* pb = Pb + (size_t)did * HID;
    int4 ga[4], gb[4];
#pragma unroll
    for (int s = 0; s < 4; ++s)
      ga[s] = *(const int4*)((const char*)pa + s * 64 + q * 16);
#pragma unroll
    for (int s = 0; s < 4; ++s)
      gb[s] = *(const int4*)((const char*)pb + s * 64 + q * 16);

    // prefetch next tile's ids (breaks ids->gather serial chain)
    const int tn = t + nw;
    int sid2 = 0, did2 = 0;
    float at2 = 0.f;
    if (tn < NT) {
      sid2 = ei[tn * 16 + l15];
      did2 = ei[E_EDGES + tn * 16 + l15];
      at2  = attr[tn * 16 + l15];
    }

    f32x4 c0 = {0.f, 0.f, 0.f, 0.f}, c1 = {0.f, 0.f, 0.f, 0.f};
    const float atv = at;
#pragma unroll
    for (int s = 0; s < 4; ++s) {
      const unsigned int* ua = (const unsigned int*)&ga[s];
      const unsigned int* ub = (const unsigned int*)&gb[s];
      const unsigned int* uw = (const unsigned int*)&w1p[s];
      int4 afi;
      unsigned int* af = (unsigned int*)&afi;
#pragma unroll
      for (int m = 0; m < 4; ++m) {
        float v0 = bflo(ua[m]) + bflo(ub[m]) + atv * bflo(uw[m]);
        float v1 = bfhi(ua[m]) + bfhi(ub[m]) + atv * bfhi(uw[m]);
        v0 = fmaxf(v0, 0.f);
        v1 = fmaxf(v1, 0.f);
        af[m] = cvtpk_bf16(v0, v1);
      }
      const s16x8 A = *(const s16x8*)&afi;
      c0 = __builtin_amdgcn_mfma_f32_16x16x32_bf16(A, B2a[s], c0, 0, 0, 0);
      c1 = __builtin_amdgcn_mfma_f32_16x16x32_bf16(A, B2b[s], c1, 0, 0, 0);
    }

    float p0 = fmaxf(c0[0] + b2a, 0.f) * w3a + fmaxf(c1[0] + b2b, 0.f) * w3b;
    float p1 = fmaxf(c0[1] + b2a, 0.f) * w3a + fmaxf(c1[1] + b2b, 0.f) * w3b;
    float p2 = fmaxf(c0[2] + b2a, 0.f) * w3a + fmaxf(c1[2] + b2b, 0.f) * w3b;
    float p3 = fmaxf(c0[3] + b2a, 0.f) * w3a + fmaxf(c1[3] + b2b, 0.f) * w3b;
#pragma unroll
    for (int off = 8; off >= 1; off >>= 1) {
      p0 += __shfl_xor(p0, off, 16);
      p1 += __shfl_xor(p1, off, 16);
      p2 += __shfl_xor(p2, off, 16);
      p3 += __shfl_xor(p3, off, 16);
    }
    if (l15 == 0) {
      float4 o4;
      o4.x = 1.f / (1.f + __expf(-(p0 + b3v)));
      o4.y = 1.f / (1.f + __expf(-(p1 + b3v)));
      o4.z = 1.f / (1.f + __expf(-(p2 + b3v)));
      o4.w = 1.f / (1.f + __expf(-(p3 + b3v)));
      *(float4*)&out[t * 16 + q * 4] = o4;
    }

    if (tn >= NT) break;
    t = tn; sid = sid2; did = did2; at = at2;
  }
}

extern "C" void kernel_launch(void* const* d_in, const int* in_sizes, int n_in,
                              void* d_out, int out_size, void* d_ws, size_t ws_size,
                              hipStream_t stream) {
  const float* x    = (const float*)d_in[0];
  const int*   ei   = (const int*)d_in[1];
  const float* attr = (const float*)d_in[2];
  const float* W1   = (const float*)d_in[3];
  const float* b1   = (const float*)d_in[4];
  const float* W2   = (const float*)d_in[5];
  const float* b2   = (const float*)d_in[6];
  const float* W3   = (const float*)d_in[7];
  const float* b3   = (const float*)d_in[8];
  float* out = (float*)d_out;

  const size_t needP = (size_t)NNODES * HID * 2 * sizeof(unsigned short); // 51.2 MB
  const size_t need1 = (size_t)NNODES * HID * sizeof(unsigned short);     // 25.6 MB
  if (ws_size >= needP) {
    unsigned short* Pa = (unsigned short*)d_ws;
    unsigned short* Pb = Pa + (size_t)NNODES * HID;
    node_precompute<<<NNODES / 32, 256, 0, stream>>>(x, W1, b1, Pa, Pb);
    edge_mlp2<<<EBLK, 256, 0, stream>>>(Pa, Pb, ei, attr, W1, W2, b2, W3, b3, out);
  } else if (ws_size >= need1) {
    unsigned short* xb = (unsigned short*)d_ws;
    cast_x_kernel<<<6250, 256, 0, stream>>>(x, xb);
    edge_mlp_kernel<<<NBLK, 256, 0, stream>>>(xb, ei, attr, W1, b1, W2, b2, W3, b3, out);
  } else {
    edge_naive<<<(E_EDGES + 255) / 256, 256, 0, stream>>>(x, ei, attr, W1, b1, W2, b2, W3, b3, out);
  }
}